// Round 1
// baseline (2108.214 us; speedup 1.0000x reference)
//
#include <hip/hip_runtime.h>

// Fused linear cross-entropy, MI355X/gfx950.
// logits = x(N,H) @ W(V,H)^T + b(V); loss = mean(logsumexp(logits) - logits[target]).
//
// R2: GEMM restructured from the 128x128 2-barrier-per-K-step form (measured 881 TF
// effective = the known ~900 TF ceiling of that structure) to the 256x256 8-phase
// schedule (T3+T4 counted vmcnt, T5 setprio, chunk-XOR swizzle kept from R1):
//   - BM=BN=256, BK=64, 8 waves (512 thr), per-wave C = 128x64 (acc[8][4] f32x4)
//   - LDS 2x double-buffered A/B K-tiles (128 KiB), staged via global_load_lds
//     one half-tile (128 rows) per phase = 2 x 16B-per-lane loads per thread
//   - raw s_barrier pairs per phase; s_waitcnt vmcnt(4) ONLY at phases 4 and 8
//     (2 half-tiles always in flight, never drained to 0 in the main loop)
//   - s_setprio(1) around each 16-MFMA cluster
// Stage/consume schedule (iter t computes K-tiles 2t (buf0, P1-4) and 2t+1 (buf1, P5-8)):
//   P1: A(buf1,h1)   P2: B(buf1,h1)    <- completes tile 2t+1 (begun P7/P8 prev iter)
//   P3: A(buf0,h0)   P4: B(buf0,h0)+W  P5: A(buf0,h1)  P6: B(buf0,h1)  <- tile 2t+2
//   P7: A(buf1,h0)   P8: B(buf1,h0)+W  <- begins tile 2t+3
//   W = s_waitcnt vmcnt(4): at P4 ensures tile 2t+1 resident before P5 reads;
//   at P8 ensures tile 2t+2 resident before next-iter P1 reads.
// Assumes (fast path) N%256==0, V%256==0, H%128==0 (holds: 4096, 32000, 4096).

#define IGNORE_INDEX (-100)

typedef unsigned short u16;
typedef __attribute__((ext_vector_type(8))) short s8b;    // 8 bf16 = 4 VGPRs (MFMA A/B frag)
typedef __attribute__((ext_vector_type(4))) float f32x4;  // MFMA C/D frag

__device__ __forceinline__ u16 f2bf(float f) {
  unsigned int u = __float_as_uint(f);
  u += 0x7FFFu + ((u >> 16) & 1u);  // round-to-nearest-even
  return (u16)(u >> 16);
}

// one float4 -> ushort4 per thread: no serial loop, pure TLP
__global__ void f32_to_bf16_kernel(const float* __restrict__ src,
                                   u16* __restrict__ dst, long n4) {
  long i = (long)blockIdx.x * blockDim.x + threadIdx.x;
  if (i >= n4) return;
  float4 v = ((const float4*)src)[i];
  ushort4 o;
  o.x = f2bf(v.x); o.y = f2bf(v.y); o.z = f2bf(v.z); o.w = f2bf(v.w);
  ((ushort4*)dst)[i] = o;
}

// async global->LDS, 16B per lane, LDS dest = wave-uniform base + lane*16
#define GLDS16(g, l)                                                     \
  __builtin_amdgcn_global_load_lds(                                      \
      (const __attribute__((address_space(1))) void*)(g),                \
      (__attribute__((address_space(3))) void*)(l), 16, 0, 0)

// =====================  256x256 8-phase GEMM (fast path)  =====================
// LDS tile layout: row r = 64 u16 = 8 chunks of 16B; global chunk c of row r at
// slot (c ^ (r&7)).  Writes stay linear (global_load_lds), source pre-swizzled.
__global__ __launch_bounds__(512, 2) void flce_gemm256(
    const u16* __restrict__ X, const u16* __restrict__ W,
    const float* __restrict__ bias, const int* __restrict__ target,
    float* __restrict__ S, float* __restrict__ tgt, int N, int V, int H) {
  __shared__ __align__(16) u16 As[2][256 * 64];  // 64 KiB: x tiles, dbuf
  __shared__ __align__(16) u16 Bs[2][256 * 64];  // 64 KiB: W tiles, dbuf
  __shared__ int tg[256];

  const int tid = threadIdx.x;
  const int w = tid >> 6;             // wave 0..7
  const int lane = tid & 63;
  const int wr = w >> 2, wc = w & 3;  // wave tile: rows wr*128.., cols wc*64..
  const int lane15 = lane & 15, quad = lane >> 4;

  // XCD-chunked bijective blockIdx swizzle (nwg % 8 == 0 for our shapes)
  const int nxb = N >> 8;
  const int nwg = gridDim.x;
  int bid = blockIdx.x;
  if ((nwg & 7) == 0) bid = (bid & 7) * (nwg >> 3) + (bid >> 3);
  const int bm = (bid % nxb) << 8;
  const int bv = (bid / nxb) << 8;

  if (tid < 256) tg[tid] = target[bm + tid];

  f32x4 acc[8][4];
  {
    f32x4 z = {0.f, 0.f, 0.f, 0.f};
#pragma unroll
    for (int i = 0; i < 8; ++i)
#pragma unroll
      for (int j = 0; j < 4; ++j) acc[i][j] = z;
  }

  // staging: each GLDS16 covers 64 rows (8 rows/wave); lane = r8*8+l8 writes
  // slot l8 of row (..+r8), so the SOURCE chunk is l8^r8 (swizzle on the read side).
  const int r8 = lane >> 3, sc8 = ((lane & 7) ^ r8) * 8;
  const u16* aB = X + (size_t)(bm + w * 8 + r8) * H + sc8;
  const u16* bB = W + (size_t)(bv + w * 8 + r8) * H + sc8;

#define STG_A(buf, h, ke)                                                        \
  do {                                                                           \
    GLDS16(aB + (size_t)((h) * 128) * H + (ke),                                  \
           &As[buf][(((h) * 128) + w * 8) * 64]);                                \
    GLDS16(aB + (size_t)((h) * 128 + 64) * H + (ke),                             \
           &As[buf][(((h) * 128 + 64) + w * 8) * 64]);                           \
  } while (0)
#define STG_B(buf, h, ke)                                                        \
  do {                                                                           \
    GLDS16(bB + (size_t)((h) * 128) * H + (ke),                                  \
           &Bs[buf][(((h) * 128) + w * 8) * 64]);                                \
    GLDS16(bB + (size_t)((h) * 128 + 64) * H + (ke),                             \
           &Bs[buf][(((h) * 128 + 64) + w * 8) * 64]);                           \
  } while (0)

  // fragment read bases; chunk for kk: kk*4+quad, swizzled by lane15&7
  const u16* A0p = &As[0][(wr * 128 + lane15) * 64];
  const u16* A1p = &As[1][(wr * 128 + lane15) * 64];
  const u16* B0p = &Bs[0][(wc * 64 + lane15) * 64];
  const u16* B1p = &Bs[1][(wc * 64 + lane15) * 64];
  const int sl0 = ((quad) ^ (lane15 & 7)) * 8;
  const int sl1 = ((4 + quad) ^ (lane15 & 7)) * 8;

#define LDS_A(dst, base, roff)                                                   \
  do {                                                                           \
    _Pragma("unroll") for (int i = 0; i < 4; ++i) {                              \
      dst[i][0] = *(const s8b*)((base) + ((roff) + i * 16) * 64 + sl0);          \
      dst[i][1] = *(const s8b*)((base) + ((roff) + i * 16) * 64 + sl1);          \
    }                                                                            \
  } while (0)
#define LDS_B(base)                                                              \
  do {                                                                           \
    _Pragma("unroll") for (int j = 0; j < 4; ++j) {                              \
      bF[j][0] = *(const s8b*)((base) + (j * 16) * 64 + sl0);                    \
      bF[j][1] = *(const s8b*)((base) + (j * 16) * 64 + sl1);                    \
    }                                                                            \
  } while (0)
#define MFMAQ(af, mh, nh)                                                        \
  do {                                                                           \
    __builtin_amdgcn_s_setprio(1);                                               \
    _Pragma("unroll") for (int kk = 0; kk < 2; ++kk)                             \
    _Pragma("unroll") for (int i = 0; i < 4; ++i)                                \
    _Pragma("unroll") for (int jj = 0; jj < 2; ++jj)                             \
        acc[(mh) * 4 + i][(nh) * 2 + jj] =                                       \
            __builtin_amdgcn_mfma_f32_16x16x32_bf16(                             \
                af[i][kk], bF[(nh) * 2 + jj][kk],                                \
                acc[(mh) * 4 + i][(nh) * 2 + jj], 0, 0, 0);                      \
    __builtin_amdgcn_s_setprio(0);                                               \
  } while (0)
#define PH_SYNC()                                                                \
  do {                                                                           \
    __builtin_amdgcn_s_barrier();                                                \
    asm volatile("s_waitcnt lgkmcnt(0)" ::: "memory");                           \
  } while (0)
#define PH_END() __builtin_amdgcn_s_barrier()

  // ---- prologue: tile0 (buf0) complete + tile1 (buf1) first halves ----
  STG_A(0, 0, 0); STG_B(0, 0, 0); STG_A(0, 1, 0); STG_B(0, 1, 0);
  STG_A(1, 0, 64); STG_B(1, 0, 64);
  asm volatile("s_waitcnt vmcnt(4)" ::: "memory");  // tile0 resident; tile1 h0 in flight
  __builtin_amdgcn_s_barrier();

  const int nPair = H >> 7;  // iterations of 2 K-tiles
  for (int t = 0; t < nPair; ++t) {
    const bool lastI = (t == nPair - 1);
    const int k1 = (2 * t + 1) << 6, k2 = (2 * t + 2) << 6, k3 = (2 * t + 3) << 6;
    s8b aE[4][2], aO[4][2], bF[4][2];

    // ---- P1: tile 2t (buf0), quadrant (mh0,nh0) ----
    LDS_A(aE, A0p, 0);
    LDS_B(B0p);
    STG_A(1, 1, k1);
    PH_SYNC();
    MFMAQ(aE, 0, 0);
    PH_END();
    // ---- P2: quadrant (mh0,nh1) ----
    LDS_A(aO, A0p, 64);
    STG_B(1, 1, k1);
    PH_SYNC();
    MFMAQ(aE, 0, 1);
    PH_END();
    // ---- P3: quadrant (mh1,nh0) ----
    if (!lastI) STG_A(0, 0, k2);
    PH_SYNC();
    MFMAQ(aO, 1, 0);
    PH_END();
    // ---- P4: quadrant (mh1,nh1); counted wait for buf1 tile ----
    if (!lastI) {
      STG_B(0, 0, k2);
      asm volatile("s_waitcnt vmcnt(4)" ::: "memory");
    } else {
      asm volatile("s_waitcnt vmcnt(0)" ::: "memory");
    }
    PH_SYNC();
    MFMAQ(aO, 1, 1);
    PH_END();
    // ---- P5: tile 2t+1 (buf1), quadrant (mh0,nh0) ----
    LDS_A(aE, A1p, 0);
    LDS_B(B1p);
    if (!lastI) STG_A(0, 1, k2);
    PH_SYNC();
    MFMAQ(aE, 0, 0);
    PH_END();
    // ---- P6: quadrant (mh0,nh1) ----
    LDS_A(aO, A1p, 64);
    if (!lastI) STG_B(0, 1, k2);
    PH_SYNC();
    MFMAQ(aE, 0, 1);
    PH_END();
    // ---- P7: quadrant (mh1,nh0) ----
    if (!lastI) STG_A(1, 0, k3);
    PH_SYNC();
    MFMAQ(aO, 1, 0);
    PH_END();
    // ---- P8: quadrant (mh1,nh1); counted wait for next-iter buf0 tile ----
    if (!lastI) {
      STG_B(1, 0, k3);
      asm volatile("s_waitcnt vmcnt(4)" ::: "memory");
    }
    PH_SYNC();
    MFMAQ(aO, 1, 1);
    PH_END();
  }

  // ---- fused epilogue: +bias, sum(exp), target capture ----
  // C/D layout (16x16): col = lane&15, row = quad*4 + reg  [m89/m91-verified]
  float(*ssum)[4] = (float(*)[4])(&As[0][0]);  // As dead after main loop
  float bj[4];
#pragma unroll
  for (int j = 0; j < 4; ++j) bj[j] = bias[bv + wc * 64 + j * 16 + lane15];
  const int cbase = bv + wc * 64 + lane15;

#pragma unroll
  for (int i = 0; i < 8; ++i) {
#pragma unroll
    for (int r = 0; r < 4; ++r) {
      const int rloc = wr * 128 + i * 16 + quad * 4 + r;  // row within 256-block
      const int rg = bm + rloc;
      const int tt = tg[rloc];
      float v0 = acc[i][0][r] + bj[0];
      float v1 = acc[i][1][r] + bj[1];
      float v2 = acc[i][2][r] + bj[2];
      float v3 = acc[i][3][r] + bj[3];
      if (cbase == tt) tgt[rg] = v0;
      if (cbase + 16 == tt) tgt[rg] = v1;
      if (cbase + 32 == tt) tgt[rg] = v2;
      if (cbase + 48 == tt) tgt[rg] = v3;
      float s = __expf(v0) + __expf(v1) + __expf(v2) + __expf(v3);
      s += __shfl_xor(s, 1, 16);
      s += __shfl_xor(s, 2, 16);
      s += __shfl_xor(s, 4, 16);
      s += __shfl_xor(s, 8, 16);
      if (lane15 == 0) ssum[rloc][wc] = s;
    }
  }
  __syncthreads();
  if (tid < 256)
    atomicAdd(&S[bm + tid], ssum[tid][0] + ssum[tid][1] + ssum[tid][2] + ssum[tid][3]);
}

// =====================  128x128 kernel (fallback paths)  =====================
// PRECONV=true : Aptr/Bptr are bf16 (u16) pre-converted in ws -> global_load_lds path.
// PRECONV=false: Aptr/Bptr are fp32 inputs -> VGPR load + cvt + ds_write staging.
template <bool PRECONV>
__global__ __launch_bounds__(256) void flce_gemm(
    const void* __restrict__ Aptr, const void* __restrict__ Bptr,
    const float* __restrict__ bias, const int* __restrict__ target,
    float* __restrict__ S, float* __restrict__ tgt, int N, int V, int H) {
  __shared__ __align__(16) u16 As2[128 * 64];
  __shared__ __align__(16) u16 Bs2[128 * 64];
  __shared__ int tg[128];
  __shared__ float ssum[128][2];

  const int tid = threadIdx.x;
  const int w = tid >> 6;
  const int lane = tid & 63;
  const int wr = w >> 1, wc = w & 1;
  const int lane15 = lane & 15, quad = lane >> 4;
  const int bm = blockIdx.x * 128;
  const int bv = blockIdx.y * 128;

  if (tid < 128) tg[tid] = target[bm + tid];

  f32x4 acc[4][4];
  {
    f32x4 z = {0.f, 0.f, 0.f, 0.f};
#pragma unroll
    for (int i = 0; i < 4; ++i)
#pragma unroll
      for (int j = 0; j < 4; ++j) acc[i][j] = z;
  }

  const u16* aSrc = nullptr;
  const u16* bSrc = nullptr;
  {
    const int r8 = lane >> 3, l8 = lane & 7;
    const int sc = l8 ^ r8;
    if constexpr (PRECONV) {
      aSrc = (const u16*)Aptr + (size_t)(bm + w * 32 + r8) * H + sc * 8;
      bSrc = (const u16*)Bptr + (size_t)(bv + w * 32 + r8) * H + sc * 8;
    }
  }
  u16* aDstW = &As2[(w * 32) * 64];
  u16* bDstW = &Bs2[(w * 32) * 64];

  for (int k0 = 0; k0 < H; k0 += 64) {
    if constexpr (PRECONV) {
#pragma unroll
      for (int t = 0; t < 4; ++t) {
        GLDS16(aSrc + (size_t)t * 8 * H, aDstW + t * 8 * 64);
        GLDS16(bSrc + (size_t)t * 8 * H, bDstW + t * 8 * 64);
      }
      aSrc += 64;
      bSrc += 64;
    } else {
      const float* Af = (const float*)Aptr;
      const float* Bf = (const float*)Bptr;
#pragma unroll
      for (int p = 0; p < 8; ++p) {
        int q = p * 256 + tid;
        int row = q >> 4;
        int c4 = q & 15;
        int chunk = c4 >> 1, half = c4 & 1;
        int dstOff = (((chunk ^ (row & 7)) << 1) | half) * 4;
        float4 va = *(const float4*)(Af + (size_t)(bm + row) * H + k0 + c4 * 4);
        float4 vb = *(const float4*)(Bf + (size_t)(bv + row) * H + k0 + c4 * 4);
        ushort4 ua, ub;
        ua.x = f2bf(va.x); ua.y = f2bf(va.y); ua.z = f2bf(va.z); ua.w = f2bf(va.w);
        ub.x = f2bf(vb.x); ub.y = f2bf(vb.y); ub.z = f2bf(vb.z); ub.w = f2bf(vb.w);
        *(ushort4*)&As2[row * 64 + dstOff] = ua;
        *(ushort4*)&Bs2[row * 64 + dstOff] = ub;
      }
    }
    __syncthreads();
#pragma unroll
    for (int kk = 0; kk < 64; kk += 32) {
      s8b af[4], bfr[4];
      const int ch = (kk >> 3) + quad;
      const int slot = (ch ^ (lane15 & 7)) * 8;
#pragma unroll
      for (int i = 0; i < 4; ++i)
        af[i] = *(const s8b*)&As2[(wr * 64 + i * 16 + lane15) * 64 + slot];
#pragma unroll
      for (int j = 0; j < 4; ++j)
        bfr[j] = *(const s8b*)&Bs2[(wc * 64 + j * 16 + lane15) * 64 + slot];
#pragma unroll
      for (int i = 0; i < 4; ++i)
#pragma unroll
        for (int j = 0; j < 4; ++j)
          acc[i][j] = __builtin_amdgcn_mfma_f32_16x16x32_bf16(af[i], bfr[j],
                                                              acc[i][j], 0, 0, 0);
    }
    __syncthreads();
  }

  float bj[4];
#pragma unroll
  for (int j = 0; j < 4; ++j) bj[j] = bias[bv + wc * 64 + j * 16 + lane15];
  const int cbase = bv + wc * 64 + lane15;

#pragma unroll
  for (int i = 0; i < 4; ++i) {
#pragma unroll
    for (int r = 0; r < 4; ++r) {
      int rloc = wr * 64 + i * 16 + quad * 4 + r;
      int rg = bm + rloc;
      int t = tg[rloc];
      float v0 = acc[i][0][r] + bj[0];
      float v1 = acc[i][1][r] + bj[1];
      float v2 = acc[i][2][r] + bj[2];
      float v3 = acc[i][3][r] + bj[3];
      if (cbase == t) tgt[rg] = v0;
      if (cbase + 16 == t) tgt[rg] = v1;
      if (cbase + 32 == t) tgt[rg] = v2;
      if (cbase + 48 == t) tgt[rg] = v3;
      float s = __expf(v0) + __expf(v1) + __expf(v2) + __expf(v3);
      s += __shfl_xor(s, 1, 16);
      s += __shfl_xor(s, 2, 16);
      s += __shfl_xor(s, 4, 16);
      s += __shfl_xor(s, 8, 16);
      if (lane15 == 0) ssum[rloc][wc] = s;
    }
  }
  __syncthreads();
  if (tid < 128) atomicAdd(&S[bm + tid], ssum[tid][0] + ssum[tid][1]);
}

__global__ void flce_final(const float* __restrict__ S, const float* __restrict__ tgt,
                           const int* __restrict__ target, float* __restrict__ out,
                           int N) {
  float sum = 0.f, cnt = 0.f;
  for (int n = threadIdx.x; n < N; n += 256) {
    int t = target[n];
    if (t != IGNORE_INDEX) {
      sum += logf(S[n]) - tgt[n];
      cnt += 1.f;
    }
  }
#pragma unroll
  for (int off = 32; off > 0; off >>= 1) {
    sum += __shfl_down(sum, off, 64);
    cnt += __shfl_down(cnt, off, 64);
  }
  __shared__ float red[8];
  if ((threadIdx.x & 63) == 0) {
    red[(threadIdx.x >> 6) * 2] = sum;
    red[(threadIdx.x >> 6) * 2 + 1] = cnt;
  }
  __syncthreads();
  if (threadIdx.x == 0) {
    float s = 0.f, c = 0.f;
    for (int i = 0; i < 4; ++i) { s += red[2 * i]; c += red[2 * i + 1]; }
    out[0] = s / c;
  }
}

extern "C" void kernel_launch(void* const* d_in, const int* in_sizes, int n_in,
                              void* d_out, int out_size, void* d_ws, size_t ws_size,
                              hipStream_t stream) {
  const float* W = (const float*)d_in[0];      // (V,H) fp32
  const float* X = (const float*)d_in[1];      // (N,H) fp32
  const int* target = (const int*)d_in[2];     // (N,) int
  const float* bias = (const float*)d_in[3];   // (V,) fp32
  float* out = (float*)d_out;

  const long VH = in_sizes[0];
  const long NH = in_sizes[1];
  const int N = in_sizes[2];
  const int V = in_sizes[3];
  const int H = (int)(NH / N);

  unsigned char* ws = (unsigned char*)d_ws;
  const size_t wbB = (size_t)VH * 2, xbB = (size_t)NH * 2;
  const size_t need = wbB + xbB + (size_t)N * 8;
  const bool ok256 = (N % 256 == 0) && (V % 256 == 0) && (H % 128 == 0);

  if (ws_size >= need) {
    u16* Wb = (u16*)ws;
    u16* Xb = (u16*)(ws + wbB);
    float* S = (float*)(ws + wbB + xbB);
    float* tgt = S + N;
    hipMemsetAsync(S, 0, (size_t)N * 8, stream);  // S + tgt
    long w4 = VH / 4, x4 = NH / 4;
    f32_to_bf16_kernel<<<(int)((w4 + 255) / 256), 256, 0, stream>>>(W, Wb, w4);
    f32_to_bf16_kernel<<<(int)((x4 + 255) / 256), 256, 0, stream>>>(X, Xb, x4);
    if (ok256) {
      int nwg = (N / 256) * (V / 256);
      flce_gemm256<<<nwg, 512, 0, stream>>>(Xb, Wb, bias, target, S, tgt, N, V, H);
    } else {
      dim3 grid(N / 128, V / 128);
      flce_gemm<true><<<grid, 256, 0, stream>>>(Xb, Wb, bias, target, S, tgt, N, V, H);
    }
    flce_final<<<1, 256, 0, stream>>>(S, tgt, target, out, N);
  } else {
    // workspace too small to pre-convert: on-the-fly fp32->bf16 staging
    float* S = (float*)ws;
    float* tgt = S + N;
    hipMemsetAsync(S, 0, (size_t)N * 8, stream);
    dim3 grid(N / 128, V / 128);
    flce_gemm<false><<<grid, 256, 0, stream>>>(X, W, bias, target, S, tgt, N, V, H);
    flce_final<<<1, 256, 0, stream>>>(S, tgt, target, out, N);
  }
}

// Round 2
// 1687.482 us; speedup vs baseline: 1.2493x; 1.2493x over previous
//
#include <hip/hip_runtime.h>

// Fused linear cross-entropy, MI355X/gfx950.
// logits = x(N,H) @ W(V,H)^T + b(V); loss = mean(logsumexp(logits) - logits[target]).
//
// R3: fixed the 8-phase schedule (R2 was a lockstep coarse split: 16/8/0/0 read
// distribution, MfmaUtil 31%). Wave output is now BANDED: rows = mh*128 + wr*64,
// cols = nh*128 + wc*32, so each phase's MFMA quadrant (mh,nh) consumes exactly one
// A half-tile and one B half-tile. Reads distribute 12/4/8/0 per K-tile and each
// half-tile stage trails its last read-issue phase by >=1 barrier pair:
//   P1: rd A0h0+B0h0, stg A1h1      | MFMA (0,0)
//   P2: rd B0h1,      stg A0h0'     | MFMA (0,1)
//   P3: rd A0h1,      stg B0h0'     | MFMA (1,0)
//   P4:               stg B0h1', vmcnt(6) | MFMA (1,1)   <- buf1 tile resident
//   P5: rd A1h0+B1h0, stg A0h1'     | MFMA (0,0)
//   P6: rd B1h1,      stg A1h0''    | MFMA (0,1)
//   P7: rd A1h1,      stg B1h0''    | MFMA (1,0)
//   P8:               stg B1h1'', vmcnt(6) | MFMA (1,1)  <- buf0 tile resident
// vmcnt(6) = 3 half-tiles (2 loads each) always in flight, never drained to 0.
// Assumes (fast path) N%256==0, V%256==0, H%128==0 (holds: 4096, 32000, 4096).

#define IGNORE_INDEX (-100)

typedef unsigned short u16;
typedef __attribute__((ext_vector_type(8))) short s8b;    // 8 bf16 = 4 VGPRs (MFMA A/B frag)
typedef __attribute__((ext_vector_type(4))) float f32x4;  // MFMA C/D frag

__device__ __forceinline__ u16 f2bf(float f) {
  unsigned int u = __float_as_uint(f);
  u += 0x7FFFu + ((u >> 16) & 1u);  // round-to-nearest-even
  return (u16)(u >> 16);
}

// one float4 -> ushort4 per thread: no serial loop, pure TLP
__global__ void f32_to_bf16_kernel(const float* __restrict__ src,
                                   u16* __restrict__ dst, long n4) {
  long i = (long)blockIdx.x * blockDim.x + threadIdx.x;
  if (i >= n4) return;
  float4 v = ((const float4*)src)[i];
  ushort4 o;
  o.x = f2bf(v.x); o.y = f2bf(v.y); o.z = f2bf(v.z); o.w = f2bf(v.w);
  ((ushort4*)dst)[i] = o;
}

// async global->LDS, 16B per lane, LDS dest = wave-uniform base + lane*16
#define GLDS16(g, l)                                                     \
  __builtin_amdgcn_global_load_lds(                                      \
      (const __attribute__((address_space(1))) void*)(g),                \
      (__attribute__((address_space(3))) void*)(l), 16, 0, 0)

// =====================  256x256 8-phase GEMM (fast path)  =====================
// LDS tile layout: row r = 64 u16 = 8 chunks of 16B; global chunk c of row r at
// slot (c ^ (r&7)).  Writes stay linear (global_load_lds), source pre-swizzled.
__global__ __launch_bounds__(512, 2) void flce_gemm256(
    const u16* __restrict__ X, const u16* __restrict__ W,
    const float* __restrict__ bias, const int* __restrict__ target,
    float* __restrict__ S, float* __restrict__ tgt, int N, int V, int H) {
  __shared__ __align__(16) u16 As[2][256 * 64];  // 64 KiB: x tiles, dbuf
  __shared__ __align__(16) u16 Bs[2][256 * 64];  // 64 KiB: W tiles, dbuf
  __shared__ int tg[256];

  const int tid = threadIdx.x;
  const int w = tid >> 6;             // wave 0..7
  const int lane = tid & 63;
  const int wr = w >> 2, wc = w & 3;  // banded: rows mh*128+wr*64, cols nh*128+wc*32
  const int lane15 = lane & 15, quad = lane >> 4;

  // XCD-chunked bijective blockIdx swizzle (nwg % 8 == 0 for our shapes)
  const int nxb = N >> 8;
  const int nwg = gridDim.x;
  int bid = blockIdx.x;
  if ((nwg & 7) == 0) bid = (bid & 7) * (nwg >> 3) + (bid >> 3);
  const int bm = (bid % nxb) << 8;
  const int bv = (bid / nxb) << 8;

  if (tid < 256) tg[tid] = target[bm + tid];

  f32x4 acc[8][4];
  {
    f32x4 z = {0.f, 0.f, 0.f, 0.f};
#pragma unroll
    for (int i = 0; i < 8; ++i)
#pragma unroll
      for (int j = 0; j < 4; ++j) acc[i][j] = z;
  }

  // staging: each GLDS16 covers 64 rows (8 rows/wave); lane = r8*8+l8 writes
  // slot l8 of row (..+r8), so the SOURCE chunk is l8^r8 (swizzle on the read side).
  const int r8 = lane >> 3, sc8 = ((lane & 7) ^ r8) * 8;
  const u16* aB = X + (size_t)(bm + w * 8 + r8) * H + sc8;
  const u16* bB = W + (size_t)(bv + w * 8 + r8) * H + sc8;

// stage one half-tile (128 rows) of A or B: 2 x GLDS16 per thread
#define STG_A(buf, h, ke)                                                        \
  do {                                                                           \
    GLDS16(aB + (size_t)((h) * 128) * H + (ke),                                  \
           &As[buf][(((h) * 128) + w * 8) * 64]);                                \
    GLDS16(aB + (size_t)((h) * 128 + 64) * H + (ke),                             \
           &As[buf][(((h) * 128 + 64) + w * 8) * 64]);                           \
  } while (0)
#define STG_B(buf, h, ke)                                                        \
  do {                                                                           \
    GLDS16(bB + (size_t)((h) * 128) * H + (ke),                                  \
           &Bs[buf][(((h) * 128) + w * 8) * 64]);                                \
    GLDS16(bB + (size_t)((h) * 128 + 64) * H + (ke),                             \
           &Bs[buf][(((h) * 128 + 64) + w * 8) * 64]);                           \
  } while (0)

  // fragment reads: swizzled chunk slots for the two K=32 halves of a row
  const int sl0 = ((quad) ^ (lane15 & 7)) * 8;
  const int sl1 = ((4 + quad) ^ (lane15 & 7)) * 8;

#define RDA(dst, buf, mh)                                                        \
  do {                                                                           \
    _Pragma("unroll") for (int i = 0; i < 4; ++i) {                              \
      const int rr = ((mh) * 128 + wr * 64 + i * 16 + lane15) * 64;              \
      dst[i][0] = *(const s8b*)&As[buf][rr + sl0];                               \
      dst[i][1] = *(const s8b*)&As[buf][rr + sl1];                               \
    }                                                                            \
  } while (0)
#define RDB(dst, buf, nh)                                                        \
  do {                                                                           \
    _Pragma("unroll") for (int j = 0; j < 2; ++j) {                              \
      const int rr = ((nh) * 128 + wc * 32 + j * 16 + lane15) * 64;              \
      dst[j][0] = *(const s8b*)&Bs[buf][rr + sl0];                               \
      dst[j][1] = *(const s8b*)&Bs[buf][rr + sl1];                               \
    }                                                                            \
  } while (0)

#define MFMAQ(af, bf, mh, nh)                                                    \
  do {                                                                           \
    __builtin_amdgcn_s_setprio(1);                                               \
    _Pragma("unroll") for (int kk = 0; kk < 2; ++kk)                             \
    _Pragma("unroll") for (int i = 0; i < 4; ++i)                                \
    _Pragma("unroll") for (int jj = 0; jj < 2; ++jj)                             \
        acc[(mh) * 4 + i][(nh) * 2 + jj] =                                       \
            __builtin_amdgcn_mfma_f32_16x16x32_bf16(                             \
                af[i][kk], bf[jj][kk], acc[(mh) * 4 + i][(nh) * 2 + jj],         \
                0, 0, 0);                                                        \
    __builtin_amdgcn_s_setprio(0);                                               \
  } while (0)
#define PH_SYNC()                                                                \
  do {                                                                           \
    __builtin_amdgcn_s_barrier();                                                \
    asm volatile("s_waitcnt lgkmcnt(0)" ::: "memory");                           \
  } while (0)
#define PH_END() __builtin_amdgcn_s_barrier()

  // ---- prologue: tile0 (buf0, 4 halves) + tile1 (buf1, first 3 halves) ----
  STG_A(0, 0, 0); STG_B(0, 0, 0); STG_B(0, 1, 0); STG_A(0, 1, 0);
  STG_A(1, 0, 64); STG_B(1, 0, 64); STG_B(1, 1, 64);
  asm volatile("s_waitcnt vmcnt(6)" ::: "memory");  // tile0 resident; 3 halves in flight
  __builtin_amdgcn_s_barrier();

  const int nPair = H >> 7;  // iterations of 2 K-tiles
  for (int t = 0; t < nPair; ++t) {
    const bool lastI = (t == nPair - 1);
    const int k1 = (2 * t + 1) << 6, k2 = (2 * t + 2) << 6, k3 = (2 * t + 3) << 6;
    s8b aE[4][2], aO[4][2], b0[2][2], b1[2][2];

    // ---- P1: tile 2t (buf0), quadrant (0,0) ----
    RDA(aE, 0, 0);
    RDB(b0, 0, 0);
    STG_A(1, 1, k1);  // last half of buf1's current tile (reads were drained prev P7)
    asm volatile("s_waitcnt lgkmcnt(8)" ::: "memory");  // 12-read phase throttle
    PH_SYNC();
    MFMAQ(aE, b0, 0, 0);
    PH_END();
    // ---- P2: quadrant (0,1) ----
    RDB(b1, 0, 1);
    if (!lastI) STG_A(0, 0, k2);  // A0h0 reads drained at P1's barrier pair
    PH_SYNC();
    MFMAQ(aE, b1, 0, 1);
    PH_END();
    // ---- P3: quadrant (1,0) ----
    RDA(aO, 0, 1);
    if (!lastI) STG_B(0, 0, k2);  // B0h0 reads drained at P1
    PH_SYNC();
    MFMAQ(aO, b0, 1, 0);
    PH_END();
    // ---- P4: quadrant (1,1); counted wait -> buf1 tile fully resident ----
    if (!lastI) {
      STG_B(0, 1, k2);  // B0h1 reads drained at P2
      asm volatile("s_waitcnt vmcnt(6)" ::: "memory");
    } else {
      asm volatile("s_waitcnt vmcnt(0)" ::: "memory");
    }
    PH_SYNC();
    MFMAQ(aO, b1, 1, 1);
    PH_END();
    // ---- P5: tile 2t+1 (buf1), quadrant (0,0) ----
    RDA(aE, 1, 0);
    RDB(b0, 1, 0);
    if (!lastI) STG_A(0, 1, k2);  // A0h1 reads drained at P3
    asm volatile("s_waitcnt lgkmcnt(8)" ::: "memory");
    PH_SYNC();
    MFMAQ(aE, b0, 0, 0);
    PH_END();
    // ---- P6: quadrant (0,1) ----
    RDB(b1, 1, 1);
    if (!lastI) STG_A(1, 0, k3);  // A1h0 reads drained at P5
    PH_SYNC();
    MFMAQ(aE, b1, 0, 1);
    PH_END();
    // ---- P7: quadrant (1,0) ----
    RDA(aO, 1, 1);
    if (!lastI) STG_B(1, 0, k3);  // B1h0 reads drained at P5
    PH_SYNC();
    MFMAQ(aO, b0, 1, 0);
    PH_END();
    // ---- P8: quadrant (1,1); counted wait -> buf0 next tile resident ----
    if (!lastI) {
      STG_B(1, 1, k3);  // B1h1 reads drained at P6
      asm volatile("s_waitcnt vmcnt(6)" ::: "memory");
    }
    PH_SYNC();
    MFMAQ(aO, b1, 1, 1);
    PH_END();
  }

  // ---- fused epilogue: +bias, sum(exp), target capture ----
  // C/D layout (16x16): col = lane&15, row = quad*4 + reg  [m89/m91-verified]
  // Banded mapping: global row = bm + (i>>2)*128 + wr*64 + (i&3)*16 + quad*4 + r
  //                 global col = bv + (j>>1)*128 + wc*32 + (j&1)*16 + lane15
  float(*ssum)[4] = (float(*)[4])(&As[0][0]);  // As dead after main loop
  float bj[4];
  int cb[4];
#pragma unroll
  for (int j = 0; j < 4; ++j) {
    cb[j] = bv + (j >> 1) * 128 + wc * 32 + (j & 1) * 16 + lane15;
    bj[j] = bias[cb[j]];
  }

#pragma unroll
  for (int i = 0; i < 8; ++i) {
#pragma unroll
    for (int r = 0; r < 4; ++r) {
      const int rloc = (i >> 2) * 128 + wr * 64 + (i & 3) * 16 + quad * 4 + r;
      const int rg = bm + rloc;
      const int tt = tg[rloc];
      float v0 = acc[i][0][r] + bj[0];
      float v1 = acc[i][1][r] + bj[1];
      float v2 = acc[i][2][r] + bj[2];
      float v3 = acc[i][3][r] + bj[3];
      if (cb[0] == tt) tgt[rg] = v0;
      if (cb[1] == tt) tgt[rg] = v1;
      if (cb[2] == tt) tgt[rg] = v2;
      if (cb[3] == tt) tgt[rg] = v3;
      float s = __expf(v0) + __expf(v1) + __expf(v2) + __expf(v3);
      s += __shfl_xor(s, 1, 16);
      s += __shfl_xor(s, 2, 16);
      s += __shfl_xor(s, 4, 16);
      s += __shfl_xor(s, 8, 16);
      if (lane15 == 0) ssum[rloc][wc] = s;
    }
  }
  __syncthreads();
  if (tid < 256)
    atomicAdd(&S[bm + tid], ssum[tid][0] + ssum[tid][1] + ssum[tid][2] + ssum[tid][3]);
}

// =====================  128x128 kernel (fallback paths)  =====================
// PRECONV=true : Aptr/Bptr are bf16 (u16) pre-converted in ws -> global_load_lds path.
// PRECONV=false: Aptr/Bptr are fp32 inputs -> VGPR load + cvt + ds_write staging.
template <bool PRECONV>
__global__ __launch_bounds__(256) void flce_gemm(
    const void* __restrict__ Aptr, const void* __restrict__ Bptr,
    const float* __restrict__ bias, const int* __restrict__ target,
    float* __restrict__ S, float* __restrict__ tgt, int N, int V, int H) {
  __shared__ __align__(16) u16 As2[128 * 64];
  __shared__ __align__(16) u16 Bs2[128 * 64];
  __shared__ int tg[128];
  __shared__ float ssum[128][2];

  const int tid = threadIdx.x;
  const int w = tid >> 6;
  const int lane = tid & 63;
  const int wr = w >> 1, wc = w & 1;
  const int lane15 = lane & 15, quad = lane >> 4;
  const int bm = blockIdx.x * 128;
  const int bv = blockIdx.y * 128;

  if (tid < 128) tg[tid] = target[bm + tid];

  f32x4 acc[4][4];
  {
    f32x4 z = {0.f, 0.f, 0.f, 0.f};
#pragma unroll
    for (int i = 0; i < 4; ++i)
#pragma unroll
      for (int j = 0; j < 4; ++j) acc[i][j] = z;
  }

  const u16* aSrc = nullptr;
  const u16* bSrc = nullptr;
  {
    const int r8 = lane >> 3, l8 = lane & 7;
    const int sc = l8 ^ r8;
    if constexpr (PRECONV) {
      aSrc = (const u16*)Aptr + (size_t)(bm + w * 32 + r8) * H + sc * 8;
      bSrc = (const u16*)Bptr + (size_t)(bv + w * 32 + r8) * H + sc * 8;
    }
  }
  u16* aDstW = &As2[(w * 32) * 64];
  u16* bDstW = &Bs2[(w * 32) * 64];

  for (int k0 = 0; k0 < H; k0 += 64) {
    if constexpr (PRECONV) {
#pragma unroll
      for (int t = 0; t < 4; ++t) {
        GLDS16(aSrc + (size_t)t * 8 * H, aDstW + t * 8 * 64);
        GLDS16(bSrc + (size_t)t * 8 * H, bDstW + t * 8 * 64);
      }
      aSrc += 64;
      bSrc += 64;
    } else {
      const float* Af = (const float*)Aptr;
      const float* Bf = (const float*)Bptr;
#pragma unroll
      for (int p = 0; p < 8; ++p) {
        int q = p * 256 + tid;
        int row = q >> 4;
        int c4 = q & 15;
        int chunk = c4 >> 1, half = c4 & 1;
        int dstOff = (((chunk ^ (row & 7)) << 1) | half) * 4;
        float4 va = *(const float4*)(Af + (size_t)(bm + row) * H + k0 + c4 * 4);
        float4 vb = *(const float4*)(Bf + (size_t)(bv + row) * H + k0 + c4 * 4);
        ushort4 ua, ub;
        ua.x = f2bf(va.x); ua.y = f2bf(va.y); ua.z = f2bf(va.z); ua.w = f2bf(va.w);
        ub.x = f2bf(vb.x); ub.y = f2bf(vb.y); ub.z = f2bf(vb.z); ub.w = f2bf(vb.w);
        *(ushort4*)&As2[row * 64 + dstOff] = ua;
        *(ushort4*)&Bs2[row * 64 + dstOff] = ub;
      }
    }
    __syncthreads();
#pragma unroll
    for (int kk = 0; kk < 64; kk += 32) {
      s8b af[4], bfr[4];
      const int ch = (kk >> 3) + quad;
      const int slot = (ch ^ (lane15 & 7)) * 8;
#pragma unroll
      for (int i = 0; i < 4; ++i)
        af[i] = *(const s8b*)&As2[(wr * 64 + i * 16 + lane15) * 64 + slot];
#pragma unroll
      for (int j = 0; j < 4; ++j)
        bfr[j] = *(const s8b*)&Bs2[(wc * 64 + j * 16 + lane15) * 64 + slot];
#pragma unroll
      for (int i = 0; i < 4; ++i)
#pragma unroll
        for (int j = 0; j < 4; ++j)
          acc[i][j] = __builtin_amdgcn_mfma_f32_16x16x32_bf16(af[i], bfr[j],
                                                              acc[i][j], 0, 0, 0);
    }
    __syncthreads();
  }

  float bj[4];
#pragma unroll
  for (int j = 0; j < 4; ++j) bj[j] = bias[bv + wc * 64 + j * 16 + lane15];
  const int cbase = bv + wc * 64 + lane15;

#pragma unroll
  for (int i = 0; i < 4; ++i) {
#pragma unroll
    for (int r = 0; r < 4; ++r) {
      int rloc = wr * 64 + i * 16 + quad * 4 + r;
      int rg = bm + rloc;
      int t = tg[rloc];
      float v0 = acc[i][0][r] + bj[0];
      float v1 = acc[i][1][r] + bj[1];
      float v2 = acc[i][2][r] + bj[2];
      float v3 = acc[i][3][r] + bj[3];
      if (cbase == t) tgt[rg] = v0;
      if (cbase + 16 == t) tgt[rg] = v1;
      if (cbase + 32 == t) tgt[rg] = v2;
      if (cbase + 48 == t) tgt[rg] = v3;
      float s = __expf(v0) + __expf(v1) + __expf(v2) + __expf(v3);
      s += __shfl_xor(s, 1, 16);
      s += __shfl_xor(s, 2, 16);
      s += __shfl_xor(s, 4, 16);
      s += __shfl_xor(s, 8, 16);
      if (lane15 == 0) ssum[rloc][wc] = s;
    }
  }
  __syncthreads();
  if (tid < 128) atomicAdd(&S[bm + tid], ssum[tid][0] + ssum[tid][1]);
}

__global__ void flce_final(const float* __restrict__ S, const float* __restrict__ tgt,
                           const int* __restrict__ target, float* __restrict__ out,
                           int N) {
  float sum = 0.f, cnt = 0.f;
  for (int n = threadIdx.x; n < N; n += 256) {
    int t = target[n];
    if (t != IGNORE_INDEX) {
      sum += logf(S[n]) - tgt[n];
      cnt += 1.f;
    }
  }
#pragma unroll
  for (int off = 32; off > 0; off >>= 1) {
    sum += __shfl_down(sum, off, 64);
    cnt += __shfl_down(cnt, off, 64);
  }
  __shared__ float red[8];
  if ((threadIdx.x & 63) == 0) {
    red[(threadIdx.x >> 6) * 2] = sum;
    red[(threadIdx.x >> 6) * 2 + 1] = cnt;
  }
  __syncthreads();
  if (threadIdx.x == 0) {
    float s = 0.f, c = 0.f;
    for (int i = 0; i < 4; ++i) { s += red[2 * i]; c += red[2 * i + 1]; }
    out[0] = s / c;
  }
}

extern "C" void kernel_launch(void* const* d_in, const int* in_sizes, int n_in,
                              void* d_out, int out_size, void* d_ws, size_t ws_size,
                              hipStream_t stream) {
  const float* W = (const float*)d_in[0];      // (V,H) fp32
  const float* X = (const float*)d_in[1];      // (N,H) fp32
  const int* target = (const int*)d_in[2];     // (N,) int
  const float* bias = (const float*)d_in[3];   // (V,) fp32
  float* out = (float*)d_out;

  const long VH = in_sizes[0];
  const long NH = in_sizes[1];
  const int N = in_sizes[2];
  const int V = in_sizes[3];
  const int H = (int)(NH / N);

  unsigned char* ws = (unsigned char*)d_ws;
  const size_t wbB = (size_t)VH * 2, xbB = (size_t)NH * 2;
  const size_t need = wbB + xbB + (size_t)N * 8;
  const bool ok256 = (N % 256 == 0) && (V % 256 == 0) && (H % 128 == 0);

  if (ws_size >= need) {
    u16* Wb = (u16*)ws;
    u16* Xb = (u16*)(ws + wbB);
    float* S = (float*)(ws + wbB + xbB);
    float* tgt = S + N;
    hipMemsetAsync(S, 0, (size_t)N * 8, stream);  // S + tgt
    long w4 = VH / 4, x4 = NH / 4;
    f32_to_bf16_kernel<<<(int)((w4 + 255) / 256), 256, 0, stream>>>(W, Wb, w4);
    f32_to_bf16_kernel<<<(int)((x4 + 255) / 256), 256, 0, stream>>>(X, Xb, x4);
    if (ok256) {
      int nwg = (N / 256) * (V / 256);
      flce_gemm256<<<nwg, 512, 0, stream>>>(Xb, Wb, bias, target, S, tgt, N, V, H);
    } else {
      dim3 grid(N / 128, V / 128);
      flce_gemm<true><<<grid, 256, 0, stream>>>(Xb, Wb, bias, target, S, tgt, N, V, H);
    }
    flce_final<<<1, 256, 0, stream>>>(S, tgt, target, out, N);
  } else {
    // workspace too small to pre-convert: on-the-fly fp32->bf16 staging
    float* S = (float*)ws;
    float* tgt = S + N;
    hipMemsetAsync(S, 0, (size_t)N * 8, stream);
    dim3 grid(N / 128, V / 128);
    flce_gemm<false><<<grid, 256, 0, stream>>>(X, W, bias, target, S, tgt, N, V, H);
    flce_final<<<1, 256, 0, stream>>>(S, tgt, target, out, N);
  }
}

// Round 3
// 1669.946 us; speedup vs baseline: 1.2624x; 1.0105x over previous
//
#include <hip/hip_runtime.h>

// Fused linear cross-entropy, MI355X/gfx950.
// logits = x(N,H) @ W(V,H)^T + b(V); loss = mean(logsumexp(logits) - logits[target]).
//
// R4: software-pipelined ds_reads one phase ahead. R3 issued each phase's fragment
// reads in the same phase (serial drain before MFMA: ~1.1K cyc/phase non-MFMA).
// Now phase p issues phase p+1's reads in its post-MFMA shadow, so reads complete
// under the MFMA cluster + barrier of the previous phase and each phase's
// lgkmcnt(0) is ~free. Buffer-switch reads (P4->P5, P8->P1) are issued after the
// vmcnt(6)+barrier that guarantees residency; per-phase asm lgkmcnt(0) "memory"
// clobbers pin all loads inside their legal window. Final iteration peeled (no
// branches in the main loop). vmcnt ledger (2 loads/STG):
//   steady state at P4/P8: 14 outstanding, vmcnt(6) drains exactly the 8 loads of
//   the tile consumed next; prologue: 14 issued, vmcnt(6) drains tile0's 8.
// Assumes (fast path) N%256==0, V%256==0, H%128==0 (holds: 4096, 32000, 4096).

#define IGNORE_INDEX (-100)

typedef unsigned short u16;
typedef __attribute__((ext_vector_type(8))) short s8b;    // 8 bf16 = 4 VGPRs (MFMA A/B frag)
typedef __attribute__((ext_vector_type(4))) float f32x4;  // MFMA C/D frag

__device__ __forceinline__ u16 f2bf(float f) {
  unsigned int u = __float_as_uint(f);
  u += 0x7FFFu + ((u >> 16) & 1u);  // round-to-nearest-even
  return (u16)(u >> 16);
}

// one float4 -> ushort4 per thread: no serial loop, pure TLP
__global__ void f32_to_bf16_kernel(const float* __restrict__ src,
                                   u16* __restrict__ dst, long n4) {
  long i = (long)blockIdx.x * blockDim.x + threadIdx.x;
  if (i >= n4) return;
  float4 v = ((const float4*)src)[i];
  ushort4 o;
  o.x = f2bf(v.x); o.y = f2bf(v.y); o.z = f2bf(v.z); o.w = f2bf(v.w);
  ((ushort4*)dst)[i] = o;
}

// async global->LDS, 16B per lane, LDS dest = wave-uniform base + lane*16
#define GLDS16(g, l)                                                     \
  __builtin_amdgcn_global_load_lds(                                      \
      (const __attribute__((address_space(1))) void*)(g),                \
      (__attribute__((address_space(3))) void*)(l), 16, 0, 0)

// =====================  256x256 8-phase GEMM (fast path)  =====================
// LDS tile layout: row r = 64 u16 = 8 chunks of 16B; global chunk c of row r at
// slot (c ^ (r&7)).  Writes stay linear (global_load_lds), source pre-swizzled.
__global__ __launch_bounds__(512, 2) void flce_gemm256(
    const u16* __restrict__ X, const u16* __restrict__ W,
    const float* __restrict__ bias, const int* __restrict__ target,
    float* __restrict__ S, float* __restrict__ tgt, int N, int V, int H) {
  __shared__ __align__(16) u16 As[2][256 * 64];  // 64 KiB: x tiles, dbuf
  __shared__ __align__(16) u16 Bs[2][256 * 64];  // 64 KiB: W tiles, dbuf
  __shared__ int tg[256];

  const int tid = threadIdx.x;
  const int w = tid >> 6;             // wave 0..7
  const int lane = tid & 63;
  const int wr = w >> 2, wc = w & 3;  // banded: rows mh*128+wr*64, cols nh*128+wc*32
  const int lane15 = lane & 15, quad = lane >> 4;

  // XCD-chunked bijective blockIdx swizzle (nwg % 8 == 0 for our shapes)
  const int nxb = N >> 8;
  const int nwg = gridDim.x;
  int bid = blockIdx.x;
  if ((nwg & 7) == 0) bid = (bid & 7) * (nwg >> 3) + (bid >> 3);
  const int bm = (bid % nxb) << 8;
  const int bv = (bid / nxb) << 8;

  if (tid < 256) tg[tid] = target[bm + tid];

  f32x4 acc[8][4];
  {
    f32x4 z = {0.f, 0.f, 0.f, 0.f};
#pragma unroll
    for (int i = 0; i < 8; ++i)
#pragma unroll
      for (int j = 0; j < 4; ++j) acc[i][j] = z;
  }

  // staging: each GLDS16 covers 64 rows (8 rows/wave); lane = r8*8+l8 writes
  // slot l8 of row (..+r8), so the SOURCE chunk is l8^r8 (swizzle on the read side).
  const int r8 = lane >> 3, sc8 = ((lane & 7) ^ r8) * 8;
  const u16* aB = X + (size_t)(bm + w * 8 + r8) * H + sc8;
  const u16* bB = W + (size_t)(bv + w * 8 + r8) * H + sc8;

// stage one half-tile (128 rows) of A or B: 2 x GLDS16 per thread
#define STG_A(buf, h, ke)                                                        \
  do {                                                                           \
    GLDS16(aB + (size_t)((h) * 128) * H + (ke),                                  \
           &As[buf][(((h) * 128) + w * 8) * 64]);                                \
    GLDS16(aB + (size_t)((h) * 128 + 64) * H + (ke),                             \
           &As[buf][(((h) * 128 + 64) + w * 8) * 64]);                           \
  } while (0)
#define STG_B(buf, h, ke)                                                        \
  do {                                                                           \
    GLDS16(bB + (size_t)((h) * 128) * H + (ke),                                  \
           &Bs[buf][(((h) * 128) + w * 8) * 64]);                                \
    GLDS16(bB + (size_t)((h) * 128 + 64) * H + (ke),                             \
           &Bs[buf][(((h) * 128 + 64) + w * 8) * 64]);                           \
  } while (0)

  // fragment reads: swizzled chunk slots for the two K=32 halves of a row
  const int sl0 = ((quad) ^ (lane15 & 7)) * 8;
  const int sl1 = ((4 + quad) ^ (lane15 & 7)) * 8;

#define RDA(dst, buf, mh)                                                        \
  do {                                                                           \
    _Pragma("unroll") for (int i = 0; i < 4; ++i) {                              \
      const int rr = ((mh) * 128 + wr * 64 + i * 16 + lane15) * 64;              \
      dst[i][0] = *(const s8b*)&As[buf][rr + sl0];                               \
      dst[i][1] = *(const s8b*)&As[buf][rr + sl1];                               \
    }                                                                            \
  } while (0)
#define RDB(dst, buf, nh)                                                        \
  do {                                                                           \
    _Pragma("unroll") for (int j = 0; j < 2; ++j) {                              \
      const int rr = ((nh) * 128 + wc * 32 + j * 16 + lane15) * 64;              \
      dst[j][0] = *(const s8b*)&Bs[buf][rr + sl0];                               \
      dst[j][1] = *(const s8b*)&Bs[buf][rr + sl1];                               \
    }                                                                            \
  } while (0)

#define MFMAQ(af, bf, mh, nh)                                                    \
  do {                                                                           \
    __builtin_amdgcn_s_setprio(1);                                               \
    _Pragma("unroll") for (int kk = 0; kk < 2; ++kk)                             \
    _Pragma("unroll") for (int i = 0; i < 4; ++i)                                \
    _Pragma("unroll") for (int jj = 0; jj < 2; ++jj)                             \
        acc[(mh) * 4 + i][(nh) * 2 + jj] =                                       \
            __builtin_amdgcn_mfma_f32_16x16x32_bf16(                             \
                af[i][kk], bf[jj][kk], acc[(mh) * 4 + i][(nh) * 2 + jj],         \
                0, 0, 0);                                                        \
    __builtin_amdgcn_s_setprio(0);                                               \
  } while (0)
#define BAR() __builtin_amdgcn_s_barrier()
#define LGKM0() asm volatile("s_waitcnt lgkmcnt(0)" ::: "memory")
#define VM6() asm volatile("s_waitcnt vmcnt(6)" ::: "memory")

  // ---- prologue: tile0 (buf0, 4 halves) + tile1 (buf1, first 3 halves) ----
  s8b aE[4][2], aO[4][2], b0[2][2], b1[2][2];
  STG_A(0, 0, 0); STG_B(0, 0, 0); STG_B(0, 1, 0); STG_A(0, 1, 0);
  STG_A(1, 0, 64); STG_B(1, 0, 64); STG_B(1, 1, 64);
  VM6();  // tile0's 8 loads drained; tile1's 6 in flight
  BAR();
  RDA(aE, 0, 0);  // pre-issue P1's reads (buf0 resident)
  RDB(b0, 0, 0);

  const int nPair = H >> 7;  // iterations of 2 K-tiles
  for (int t = 0; t < nPair - 1; ++t) {
    const int k1 = (2 * t + 1) << 6, k2 = (2 * t + 2) << 6, k3 = (2 * t + 3) << 6;
    // ---- P1: tile 2t (buf0), quadrant (0,0); pre-issue b1 ----
    STG_A(1, 1, k1);
    BAR(); LGKM0();
    MFMAQ(aE, b0, 0, 0);
    RDB(b1, 0, 1);
    BAR();
    // ---- P2: quadrant (0,1); pre-issue aO ----
    STG_A(0, 0, k2);
    BAR(); LGKM0();
    MFMAQ(aE, b1, 0, 1);
    RDA(aO, 0, 1);
    BAR();
    // ---- P3: quadrant (1,0) ----
    STG_B(0, 0, k2);
    BAR(); LGKM0();
    MFMAQ(aO, b0, 1, 0);
    BAR();
    // ---- P4: quadrant (1,1); vmcnt -> buf1 tile resident; pre-issue aE+b0 ----
    STG_B(0, 1, k2);
    VM6();
    BAR(); LGKM0();
    MFMAQ(aO, b1, 1, 1);
    RDA(aE, 1, 0);
    RDB(b0, 1, 0);
    BAR();
    // ---- P5: tile 2t+1 (buf1), quadrant (0,0); pre-issue b1 ----
    STG_A(0, 1, k2);
    BAR(); LGKM0();
    MFMAQ(aE, b0, 0, 0);
    RDB(b1, 1, 1);
    BAR();
    // ---- P6: quadrant (0,1); pre-issue aO ----
    STG_A(1, 0, k3);
    BAR(); LGKM0();
    MFMAQ(aE, b1, 0, 1);
    RDA(aO, 1, 1);
    BAR();
    // ---- P7: quadrant (1,0) ----
    STG_B(1, 0, k3);
    BAR(); LGKM0();
    MFMAQ(aO, b0, 1, 0);
    BAR();
    // ---- P8: quadrant (1,1); vmcnt -> buf0 next tile resident; pre-issue ----
    STG_B(1, 1, k3);
    VM6();
    BAR(); LGKM0();
    MFMAQ(aO, b1, 1, 1);
    RDA(aE, 0, 0);
    RDB(b0, 0, 0);
    BAR();
  }
  // ---- peeled final iteration (tiles H-128 (buf0) and H-64 (buf1)) ----
  {
    STG_A(1, 1, H - 64);  // last half of the last tile
    BAR(); LGKM0();
    MFMAQ(aE, b0, 0, 0);
    RDB(b1, 0, 1);
    BAR();
    BAR(); LGKM0();
    MFMAQ(aE, b1, 0, 1);
    RDA(aO, 0, 1);
    BAR();
    BAR(); LGKM0();
    MFMAQ(aO, b0, 1, 0);
    BAR();
    asm volatile("s_waitcnt vmcnt(0)" ::: "memory");
    BAR(); LGKM0();
    MFMAQ(aO, b1, 1, 1);
    RDA(aE, 1, 0);
    RDB(b0, 1, 0);
    BAR();
    BAR(); LGKM0();
    MFMAQ(aE, b0, 0, 0);
    RDB(b1, 1, 1);
    BAR();
    BAR(); LGKM0();
    MFMAQ(aE, b1, 0, 1);
    RDA(aO, 1, 1);
    BAR();
    BAR(); LGKM0();
    MFMAQ(aO, b0, 1, 0);
    BAR();
    BAR(); LGKM0();
    MFMAQ(aO, b1, 1, 1);
    BAR();
  }

  // ---- fused epilogue: +bias, sum(exp), target capture ----
  // C/D layout (16x16): col = lane&15, row = quad*4 + reg  [m89/m91-verified]
  // Banded mapping: global row = bm + (i>>2)*128 + wr*64 + (i&3)*16 + quad*4 + r
  //                 global col = bv + (j>>1)*128 + wc*32 + (j&1)*16 + lane15
  float(*ssum)[4] = (float(*)[4])(&As[0][0]);  // As dead after main loop
  float bj[4];
  int cb[4];
#pragma unroll
  for (int j = 0; j < 4; ++j) {
    cb[j] = bv + (j >> 1) * 128 + wc * 32 + (j & 1) * 16 + lane15;
    bj[j] = bias[cb[j]];
  }

#pragma unroll
  for (int i = 0; i < 8; ++i) {
#pragma unroll
    for (int r = 0; r < 4; ++r) {
      const int rloc = (i >> 2) * 128 + wr * 64 + (i & 3) * 16 + quad * 4 + r;
      const int rg = bm + rloc;
      const int tt = tg[rloc];
      float v0 = acc[i][0][r] + bj[0];
      float v1 = acc[i][1][r] + bj[1];
      float v2 = acc[i][2][r] + bj[2];
      float v3 = acc[i][3][r] + bj[3];
      if (cb[0] == tt) tgt[rg] = v0;
      if (cb[1] == tt) tgt[rg] = v1;
      if (cb[2] == tt) tgt[rg] = v2;
      if (cb[3] == tt) tgt[rg] = v3;
      float s = __expf(v0) + __expf(v1) + __expf(v2) + __expf(v3);
      s += __shfl_xor(s, 1, 16);
      s += __shfl_xor(s, 2, 16);
      s += __shfl_xor(s, 4, 16);
      s += __shfl_xor(s, 8, 16);
      if (lane15 == 0) ssum[rloc][wc] = s;
    }
  }
  __syncthreads();
  if (tid < 256)
    atomicAdd(&S[bm + tid], ssum[tid][0] + ssum[tid][1] + ssum[tid][2] + ssum[tid][3]);
}

// =====================  128x128 kernel (fallback paths)  =====================
// PRECONV=true : Aptr/Bptr are bf16 (u16) pre-converted in ws -> global_load_lds path.
// PRECONV=false: Aptr/Bptr are fp32 inputs -> VGPR load + cvt + ds_write staging.
template <bool PRECONV>
__global__ __launch_bounds__(256) void flce_gemm(
    const void* __restrict__ Aptr, const void* __restrict__ Bptr,
    const float* __restrict__ bias, const int* __restrict__ target,
    float* __restrict__ S, float* __restrict__ tgt, int N, int V, int H) {
  __shared__ __align__(16) u16 As2[128 * 64];
  __shared__ __align__(16) u16 Bs2[128 * 64];
  __shared__ int tg[128];
  __shared__ float ssum[128][2];

  const int tid = threadIdx.x;
  const int w = tid >> 6;
  const int lane = tid & 63;
  const int wr = w >> 1, wc = w & 1;
  const int lane15 = lane & 15, quad = lane >> 4;
  const int bm = blockIdx.x * 128;
  const int bv = blockIdx.y * 128;

  if (tid < 128) tg[tid] = target[bm + tid];

  f32x4 acc[4][4];
  {
    f32x4 z = {0.f, 0.f, 0.f, 0.f};
#pragma unroll
    for (int i = 0; i < 4; ++i)
#pragma unroll
      for (int j = 0; j < 4; ++j) acc[i][j] = z;
  }

  const u16* aSrc = nullptr;
  const u16* bSrc = nullptr;
  {
    const int r8 = lane >> 3, l8 = lane & 7;
    const int sc = l8 ^ r8;
    if constexpr (PRECONV) {
      aSrc = (const u16*)Aptr + (size_t)(bm + w * 32 + r8) * H + sc * 8;
      bSrc = (const u16*)Bptr + (size_t)(bv + w * 32 + r8) * H + sc * 8;
    }
  }
  u16* aDstW = &As2[(w * 32) * 64];
  u16* bDstW = &Bs2[(w * 32) * 64];

  for (int k0 = 0; k0 < H; k0 += 64) {
    if constexpr (PRECONV) {
#pragma unroll
      for (int t = 0; t < 4; ++t) {
        GLDS16(aSrc + (size_t)t * 8 * H, aDstW + t * 8 * 64);
        GLDS16(bSrc + (size_t)t * 8 * H, bDstW + t * 8 * 64);
      }
      aSrc += 64;
      bSrc += 64;
    } else {
      const float* Af = (const float*)Aptr;
      const float* Bf = (const float*)Bptr;
#pragma unroll
      for (int p = 0; p < 8; ++p) {
        int q = p * 256 + tid;
        int row = q >> 4;
        int c4 = q & 15;
        int chunk = c4 >> 1, half = c4 & 1;
        int dstOff = (((chunk ^ (row & 7)) << 1) | half) * 4;
        float4 va = *(const float4*)(Af + (size_t)(bm + row) * H + k0 + c4 * 4);
        float4 vb = *(const float4*)(Bf + (size_t)(bv + row) * H + k0 + c4 * 4);
        ushort4 ua, ub;
        ua.x = f2bf(va.x); ua.y = f2bf(va.y); ua.z = f2bf(va.z); ua.w = f2bf(va.w);
        ub.x = f2bf(vb.x); ub.y = f2bf(vb.y); ub.z = f2bf(vb.z); ub.w = f2bf(vb.w);
        *(ushort4*)&As2[row * 64 + dstOff] = ua;
        *(ushort4*)&Bs2[row * 64 + dstOff] = ub;
      }
    }
    __syncthreads();
#pragma unroll
    for (int kk = 0; kk < 64; kk += 32) {
      s8b af[4], bfr[4];
      const int ch = (kk >> 3) + quad;
      const int slot = (ch ^ (lane15 & 7)) * 8;
#pragma unroll
      for (int i = 0; i < 4; ++i)
        af[i] = *(const s8b*)&As2[(wr * 64 + i * 16 + lane15) * 64 + slot];
#pragma unroll
      for (int j = 0; j < 4; ++j)
        bfr[j] = *(const s8b*)&Bs2[(wc * 64 + j * 16 + lane15) * 64 + slot];
#pragma unroll
      for (int i = 0; i < 4; ++i)
#pragma unroll
        for (int j = 0; j < 4; ++j)
          acc[i][j] = __builtin_amdgcn_mfma_f32_16x16x32_bf16(af[i], bfr[j],
                                                              acc[i][j], 0, 0, 0);
    }
    __syncthreads();
  }

  float bj[4];
#pragma unroll
  for (int j = 0; j < 4; ++j) bj[j] = bias[bv + wc * 64 + j * 16 + lane15];
  const int cbase = bv + wc * 64 + lane15;

#pragma unroll
  for (int i = 0; i < 4; ++i) {
#pragma unroll
    for (int r = 0; r < 4; ++r) {
      int rloc = wr * 64 + i * 16 + quad * 4 + r;
      int rg = bm + rloc;
      int t = tg[rloc];
      float v0 = acc[i][0][r] + bj[0];
      float v1 = acc[i][1][r] + bj[1];
      float v2 = acc[i][2][r] + bj[2];
      float v3 = acc[i][3][r] + bj[3];
      if (cbase == t) tgt[rg] = v0;
      if (cbase + 16 == t) tgt[rg] = v1;
      if (cbase + 32 == t) tgt[rg] = v2;
      if (cbase + 48 == t) tgt[rg] = v3;
      float s = __expf(v0) + __expf(v1) + __expf(v2) + __expf(v3);
      s += __shfl_xor(s, 1, 16);
      s += __shfl_xor(s, 2, 16);
      s += __shfl_xor(s, 4, 16);
      s += __shfl_xor(s, 8, 16);
      if (lane15 == 0) ssum[rloc][wc] = s;
    }
  }
  __syncthreads();
  if (tid < 128) atomicAdd(&S[bm + tid], ssum[tid][0] + ssum[tid][1]);
}

__global__ void flce_final(const float* __restrict__ S, const float* __restrict__ tgt,
                           const int* __restrict__ target, float* __restrict__ out,
                           int N) {
  float sum = 0.f, cnt = 0.f;
  for (int n = threadIdx.x; n < N; n += 256) {
    int t = target[n];
    if (t != IGNORE_INDEX) {
      sum += logf(S[n]) - tgt[n];
      cnt += 1.f;
    }
  }
#pragma unroll
  for (int off = 32; off > 0; off >>= 1) {
    sum += __shfl_down(sum, off, 64);
    cnt += __shfl_down(cnt, off, 64);
  }
  __shared__ float red[8];
  if ((threadIdx.x & 63) == 0) {
    red[(threadIdx.x >> 6) * 2] = sum;
    red[(threadIdx.x >> 6) * 2 + 1] = cnt;
  }
  __syncthreads();
  if (threadIdx.x == 0) {
    float s = 0.f, c = 0.f;
    for (int i = 0; i < 4; ++i) { s += red[2 * i]; c += red[2 * i + 1]; }
    out[0] = s / c;
  }
}

extern "C" void kernel_launch(void* const* d_in, const int* in_sizes, int n_in,
                              void* d_out, int out_size, void* d_ws, size_t ws_size,
                              hipStream_t stream) {
  const float* W = (const float*)d_in[0];      // (V,H) fp32
  const float* X = (const float*)d_in[1];      // (N,H) fp32
  const int* target = (const int*)d_in[2];     // (N,) int
  const float* bias = (const float*)d_in[3];   // (V,) fp32
  float* out = (float*)d_out;

  const long VH = in_sizes[0];
  const long NH = in_sizes[1];
  const int N = in_sizes[2];
  const int V = in_sizes[3];
  const int H = (int)(NH / N);

  unsigned char* ws = (unsigned char*)d_ws;
  const size_t wbB = (size_t)VH * 2, xbB = (size_t)NH * 2;
  const size_t need = wbB + xbB + (size_t)N * 8;
  const bool ok256 = (N % 256 == 0) && (V % 256 == 0) && (H % 128 == 0);

  if (ws_size >= need) {
    u16* Wb = (u16*)ws;
    u16* Xb = (u16*)(ws + wbB);
    float* S = (float*)(ws + wbB + xbB);
    float* tgt = S + N;
    hipMemsetAsync(S, 0, (size_t)N * 8, stream);  // S + tgt
    long w4 = VH / 4, x4 = NH / 4;
    f32_to_bf16_kernel<<<(int)((w4 + 255) / 256), 256, 0, stream>>>(W, Wb, w4);
    f32_to_bf16_kernel<<<(int)((x4 + 255) / 256), 256, 0, stream>>>(X, Xb, x4);
    if (ok256) {
      int nwg = (N / 256) * (V / 256);
      flce_gemm256<<<nwg, 512, 0, stream>>>(Xb, Wb, bias, target, S, tgt, N, V, H);
    } else {
      dim3 grid(N / 128, V / 128);
      flce_gemm<true><<<grid, 256, 0, stream>>>(Xb, Wb, bias, target, S, tgt, N, V, H);
    }
    flce_final<<<1, 256, 0, stream>>>(S, tgt, target, out, N);
  } else {
    // workspace too small to pre-convert: on-the-fly fp32->bf16 staging
    float* S = (float*)ws;
    float* tgt = S + N;
    hipMemsetAsync(S, 0, (size_t)N * 8, stream);
    dim3 grid(N / 128, V / 128);
    flce_gemm<false><<<grid, 256, 0, stream>>>(X, W, bias, target, S, tgt, N, V, H);
    flce_final<<<1, 256, 0, stream>>>(S, tgt, target, out, N);
  }
}